// Round 6
// baseline (847.633 us; speedup 1.0000x reference)
//
#include <hip/hip_runtime.h>

typedef __bf16 bf16x8 __attribute__((ext_vector_type(8)));
typedef float  f32x4  __attribute__((ext_vector_type(4)));
typedef unsigned short us8 __attribute__((ext_vector_type(8)));

__device__ __forceinline__ unsigned short f2bf(float f) {
    union { float f; unsigned u; } c; c.f = f;
    unsigned u = c.u;
    u += 0x7FFFu + ((u >> 16) & 1u);   // RNE; inputs finite
    return (unsigned short)(u >> 16);
}
__device__ __forceinline__ float sigf(float v) { return 1.0f / (1.0f + __expf(-v)); }

// async 16B global -> LDS (dest = wave-uniform base + lane*16)
__device__ __forceinline__ void gl2lds16(const void* g, void* l) {
    __builtin_amdgcn_global_load_lds(
        (const __attribute__((address_space(1))) unsigned int*)g,
        (__attribute__((address_space(3))) unsigned int*)l, 16, 0, 0);
}

// -------- wxform: OIHW f32 -> [tap][co][ci] bf16 (plain, 16 KB/tap) --------
__global__ void __launch_bounds__(256) wxform(const float* __restrict__ W,
                                              unsigned short* __restrict__ wpad) {
    int o = blockIdx.x * 256 + threadIdx.x;        // 9*128*64 = 73728
    if (o < 9 * 8192) {
        int tap = o >> 13;
        int r   = o & 8191;
        int co  = r >> 6, ci = r & 63;
        wpad[o] = f2bf(W[co * 576 + ci * 9 + tap]);   // W[co][ci][kh][kw]
    }
}

// -------- xpose: NCHW f32 -> [n][h][w][slot] bf16, slot = g ^ ((w>>1)&7) ----
// Pixel (h,w) occupies 128 contiguous bytes; granule g (8 ci) at slot g^key.
// Key uses only w (block-independent: conv tiles start at w0 % 16 == 0), so
// conv3 stages rows with LINEAR global_load_lds and reads conflict-free b128.
__global__ void __launch_bounds__(256) xpose(const float* __restrict__ x,
                                             unsigned short* __restrict__ xb) {
    int t = blockIdx.x * 256 + threadIdx.x;   // 262144 = 64n * 128h * 32 wquads
    int n = t >> 12, rem = t & 4095;
    int h = rem >> 5, w4 = (rem & 31) << 2;
    const float* src = x + (size_t)n * 1048576 + h * 128 + w4;
    unsigned short* dst = xb + (size_t)(n * 16384 + h * 128 + w4) * 64;
    #pragma unroll
    for (int g = 0; g < 8; ++g) {
        float4 v[8];
        #pragma unroll
        for (int j = 0; j < 8; ++j)
            v[j] = *(const float4*)(src + (size_t)(g * 8 + j) * 16384);
        #pragma unroll
        for (int k = 0; k < 4; ++k) {
            us8 o;
            #pragma unroll
            for (int j = 0; j < 8; ++j) o[j] = f2bf((&v[j].x)[k]);
            int slot = g ^ (((w4 + k) >> 1) & 7);
            *(us8*)(dst + k * 64 + slot * 8) = o;
        }
    }
}

// ===================== conv3: reg-weights + gl2lds x-ring ====================
// Block 256 thr = 4 waves (wave = 32-co slice). Tile = 4 rows x 16 cols x 128co;
// strip of 8 tiles (32 rows). x-ring: 10 rows x 18 px x 128 B in LDS, staged by
// pure global_load_lds (3 overlapping 1KB chunks/row). Weights never touch LDS:
// per-tap B-frags live in registers, double-buffered from L2-resident wpad.
// ONE barrier per tile; no per-tap drains.
struct SmemT { unsigned short x[10 * 18 * 64]; };   // 23040 B -> 4 blocks/CU

__global__ void __launch_bounds__(256, 4)
conv3(const unsigned short* __restrict__ xb,
      const unsigned short* __restrict__ wpad,
      const float* __restrict__ bias,
      float* __restrict__ out)
{
    __shared__ __align__(16) SmemT sm;
    __shared__ float red[4];

    const int tid = threadIdx.x;
    const int coq = tid >> 6;         // wave id = co quad (32 co)
    const int lane = tid & 63;
    const int lq = lane >> 4;
    const int lm = lane & 15;

    const int ct  = blockIdx.x;       // 0..7  col tile (16 wide)
    const int rtg = blockIdx.y;       // 0..3  row strip (32 tall)
    const int n   = blockIdx.z;       // 0..63 image

    const int h0s = rtg * 32;
    const int w0  = ct * 16;
    const char* xnb = (const char*)xb + (size_t)(n * 16384) * 128 + (size_t)w0 * 128;

    // ---- prologue: stage rows h0s..h0s+5 into ring slots (h%10) ----
    for (int r = coq; r < 6; r += 4) {
        int h = h0s + r;                               // <= 101, in-bounds
        const char* srcr = xnb + (size_t)h * 16384;    // row stride 128px*128B
        char* dstr = (char*)sm.x + (h % 10) * 2304;
        gl2lds16(srcr + lane * 16,        dstr);
        gl2lds16(srcr + 1024 + lane * 16, dstr + 1024);
        gl2lds16(srcr + 1280 + lane * 16, dstr + 1280);   // overlap-tail, benign
    }

    // ---- per-lane weight reg base: co = coq*32 + ntl*16 + lm ----
    const char* wb = (const char*)wpad + ((coq * 32 + lm) << 7) + (lq << 4);
    us8 bbuf[2][4];                    // [parity][ntl*2+kc], all indices static
    #pragma unroll
    for (int f = 0; f < 4; ++f)
        bbuf[0][f] = *(const us8*)(wb + (f >> 1) * 2048 + (f & 1) * 64);   // tap 0

    float bv[2] = { bias[coq * 32 + lm], bias[coq * 32 + 16 + lm] };

    // A-frag byte offsets within a ring row: depend on (kw,kc) + lane only
    int sloff[3][2];
    #pragma unroll
    for (int kw = 0; kw < 3; ++kw)
        #pragma unroll
        for (int kc = 0; kc < 2; ++kc)
            sloff[kw][kc] = (lm + kw) * 128 +
                ((((kc << 2) | lq) ^ (((lm + kw) >> 1) & 7)) << 4);

    f32x4 acc[4][2];
    #pragma unroll
    for (int rr = 0; rr < 4; ++rr) {
        acc[rr][0] = (f32x4){0.f, 0.f, 0.f, 0.f};
        acc[rr][1] = (f32x4){0.f, 0.f, 0.f, 0.f};
    }
    float part = 0.0f;

    __syncthreads();   // prologue x visible

    int sb = h0s % 10;                 // ring slot of tile row 0
    for (int s = 0; s < 8; ++s) {
        // ---- stage next tile's 4 rows (slots sb+6..sb+9, disjoint from reads)
        if (s < 7) {
            int h = h0s + s * 4 + 6 + coq;             // may be 128/129 at edge:
            const char* srcr = xnb + (size_t)h * 16384; // reads slack, discarded
            int so = sb + 6 + coq; if (so >= 10) so -= 10;
            char* dstr = (char*)sm.x + so * 2304;
            gl2lds16(srcr + lane * 16,        dstr);
            gl2lds16(srcr + 1024 + lane * 16, dstr + 1024);
            gl2lds16(srcr + 1280 + lane * 16, dstr + 1280);
        }

        // ---- 9 taps, no barriers; B reg-double-buffered from L2 ----
        #pragma unroll
        for (int tap = 0; tap < 9; ++tap) {
            const int kh = tap / 3, kw = tap % 3;
            const int tn = (tap == 8) ? 0 : tap + 1;
            #pragma unroll
            for (int f = 0; f < 4; ++f)      // prefetch next tap's B frags
                bbuf[(tap + 1) & 1][f] =
                    *(const us8*)(wb + tn * 16384 + (f >> 1) * 2048 + (f & 1) * 64);

            int q = sb + kh; if (q >= 10) q -= 10;
            #pragma unroll
            for (int kc = 0; kc < 2; ++kc) {
                bf16x8 a[4];
                #pragma unroll
                for (int rr = 0; rr < 4; ++rr) {
                    int so = q + rr; if (so >= 10) so -= 10;
                    a[rr] = *(const bf16x8*)((const char*)sm.x + so * 2304 + sloff[kw][kc]);
                }
                #pragma unroll
                for (int ntl = 0; ntl < 2; ++ntl) {
                    union { us8 u; bf16x8 b; } bu; bu.u = bbuf[tap & 1][ntl * 2 + kc];
                    #pragma unroll
                    for (int rr = 0; rr < 4; ++rr)
                        acc[rr][ntl] = __builtin_amdgcn_mfma_f32_16x16x32_bf16(
                            a[rr], bu.b, acc[rr][ntl], 0, 0, 0);
                }
            }
        }
        #pragma unroll
        for (int f = 0; f < 4; ++f) bbuf[0][f] = bbuf[1][f];   // restore parity

        // ---- per-tile epilogue: pool + bias + sigmoid ----
        #pragma unroll
        for (int p = 0; p < 2; ++p) {
            int ph = rtg * 16 + s * 2 + p;              // pool row
            if (ph < 63) {
                int pwb = ct * 8 + lq * 2;
                #pragma unroll
                for (int ntl = 0; ntl < 2; ++ntl) {
                    f32x4 sv = acc[2 * p][ntl] + acc[2 * p + 1][ntl];  // vert pool
                    float p0 = sv[0] + sv[1];                          // cols (0,1)
                    float p1 = sv[2] + sv[3];                          // cols (2,3)
                    float bbv = bv[ntl];
                    if (pwb < 63)     part += sigf(0.25f * p0 + bbv);
                    if (pwb + 1 < 63) part += sigf(0.25f * p1 + bbv);
                }
            }
        }
        #pragma unroll
        for (int rr = 0; rr < 4; ++rr) {
            acc[rr][0] = (f32x4){0.f, 0.f, 0.f, 0.f};
            acc[rr][1] = (f32x4){0.f, 0.f, 0.f, 0.f};
        }

        sb += 4; if (sb >= 10) sb -= 10;
        __syncthreads();   // staged rows visible; read-done slots reusable
    }

    // ---- block reduce -> one atomicAdd per block ----
    #pragma unroll
    for (int off = 32; off > 0; off >>= 1)
        part += __shfl_down(part, off, 64);
    if (lane == 0) red[coq] = part;
    __syncthreads();
    if (tid == 0) atomicAdd(&out[n], red[0] + red[1] + red[2] + red[3]);
}

// ============== fallback (ws too small): v4 structure, no setprio ==========
struct SmemFB {
    unsigned short x[340 * 64];      // 43520 B
    unsigned short w[2][8192];       // 32768 B
};
__global__ void __launch_bounds__(256, 2)
conv_fb(const float* __restrict__ x, const unsigned short* __restrict__ wpad,
        const float* __restrict__ bias, float* __restrict__ out)
{
    __shared__ __align__(16) SmemFB sm;
    __shared__ float red[4];
    const int tid = threadIdx.x, wave = tid >> 6, lane = tid & 63;
    const int lq = lane >> 4, lm = lane & 15;
    const int ct = blockIdx.x, rt = blockIdx.y, n = blockIdx.z;
    const int h0 = rt * 8, w0 = ct * 32;
    const float* xn = x + (size_t)n * 1048576;

    for (int c = wave; c < 16; c += 4)
        gl2lds16(wpad + c * 512 + lane * 8, &sm.w[0][c * 512]);

    for (int it = 0; it < 6; ++it) {
        int t = it * 256 + tid;
        if (t < 1360) {
            int g = t / 170, pp = t % 170;
            int hh = pp / 17, wq = pp % 17;
            int h = h0 + hh, w = w0 + wq * 2;
            bool ok = (h < 128) && (w < 128);
            const float* src = xn + (size_t)(g * 8) * 16384 + h * 128 + w;
            us8 ua, ub;
            #pragma unroll
            for (int j = 0; j < 8; ++j) {
                float2 v = ok ? *(const float2*)(src + j * 16384) : make_float2(0.f, 0.f);
                ua[j] = f2bf(v.x); ub[j] = f2bf(v.y);
            }
            int px = hh * 34 + wq * 2;
            int key = (px >> 1) & 7;
            char* base = (char*)sm.x + px * 128 + ((g ^ key) << 4);
            *(us8*)(base) = ua; *(us8*)(base + 128) = ub;
        }
    }
    float bv[8];
    #pragma unroll
    for (int nt = 0; nt < 8; ++nt) bv[nt] = bias[nt * 16 + lm];
    f32x4 acc[4][8];
    #pragma unroll
    for (int mt = 0; mt < 4; ++mt)
        #pragma unroll
        for (int nt = 0; nt < 8; ++nt) acc[mt][nt] = (f32x4){0.f,0.f,0.f,0.f};
    __syncthreads();
    for (int tap = 0; tap < 9; ++tap) {
        const int cur = tap & 1;
        if (tap < 8) {
            const unsigned short* wt = wpad + (tap + 1) * 8192;
            for (int c = wave; c < 16; c += 4)
                gl2lds16(wt + c * 512 + lane * 8, &sm.w[cur ^ 1][c * 512]);
        }
        const int kh = tap / 3, kw = tap - kh * 3;
        bf16x8 a[2][2][2];
        #pragma unroll
        for (int rl = 0; rl < 2; ++rl)
            #pragma unroll
            for (int ch = 0; ch < 2; ++ch)
                #pragma unroll
                for (int kc = 0; kc < 2; ++kc) {
                    int px = (2 * wave + rl + kh) * 34 + ch * 16 + lm + kw;
                    int slot = ((kc << 2) | lq) ^ ((px >> 1) & 7);
                    a[rl][ch][kc] = *(const bf16x8*)((const char*)sm.x + px * 128 + (slot << 4));
                }
        #pragma unroll
        for (int nt = 0; nt < 8; ++nt) {
            #pragma unroll
            for (int kc = 0; kc < 2; ++kc) {
                bf16x8 b = *(const bf16x8*)((const char*)sm.w[cur] + (nt * 16 + lm) * 128 + kc * 64 + lq * 16);
                #pragma unroll
                for (int rl = 0; rl < 2; ++rl)
                    #pragma unroll
                    for (int ch = 0; ch < 2; ++ch)
                        acc[rl * 2 + ch][nt] = __builtin_amdgcn_mfma_f32_16x16x32_bf16(
                            a[rl][ch][kc], b, acc[rl * 2 + ch][nt], 0, 0, 0);
            }
        }
        __syncthreads();
    }
    float part = 0.0f;
    const int ph = rt * 4 + wave;
    if (ph < 63) {
        #pragma unroll
        for (int ch = 0; ch < 2; ++ch) {
            const int pwb = ct * 16 + ch * 8 + lq * 2;
            #pragma unroll
            for (int nt = 0; nt < 8; ++nt) {
                f32x4 s = acc[ch][nt] + acc[2 + ch][nt];
                float p0 = s[0] + s[1], p1 = s[2] + s[3], bb = bv[nt];
                if (pwb < 63)     part += sigf(0.25f * p0 + bb);
                if (pwb + 1 < 63) part += sigf(0.25f * p1 + bb);
            }
        }
    }
    #pragma unroll
    for (int off = 32; off > 0; off >>= 1) part += __shfl_down(part, off, 64);
    if (lane == 0) red[wave] = part;
    __syncthreads();
    if (tid == 0) atomicAdd(&out[n], red[0] + red[1] + red[2] + red[3]);
}

extern "C" void kernel_launch(void* const* d_in, const int* in_sizes, int n_in,
                              void* d_out, int out_size, void* d_ws, size_t ws_size,
                              hipStream_t stream) {
    const float* x = (const float*)d_in[0];
    const float* W = (const float*)d_in[1];
    const float* b = (const float*)d_in[2];
    float* out = (float*)d_out;

    const size_t WOFF   = 134217728ull + 65536ull;   // x' (128 MiB) + OOB slack
    const size_t NEEDED = WOFF + 9 * 8192 * 2;       // + wpad 147,456 B

    hipMemsetAsync(d_out, 0, 64 * sizeof(float), stream);

    if (ws_size >= NEEDED) {
        unsigned short* xbf  = (unsigned short*)d_ws;
        unsigned short* wpad = (unsigned short*)((char*)d_ws + WOFF);
        wxform<<<288, 256, 0, stream>>>(W, wpad);
        xpose<<<1024, 256, 0, stream>>>(x, xbf);
        conv3<<<dim3(8, 4, 64), 256, 0, stream>>>(xbf, wpad, b, out);
    } else {
        unsigned short* wpad = (unsigned short*)d_ws;
        wxform<<<288, 256, 0, stream>>>(W, wpad);
        conv_fb<<<dim3(4, 16, 64), 256, 0, stream>>>(x, wpad, b, out);
    }
}

// Round 8
// 834.190 us; speedup vs baseline: 1.0161x; 1.0161x over previous
//
#include <hip/hip_runtime.h>

typedef __bf16 bf16x8 __attribute__((ext_vector_type(8)));
typedef float  f32x4  __attribute__((ext_vector_type(4)));
typedef unsigned short us8 __attribute__((ext_vector_type(8)));

__device__ __forceinline__ unsigned short f2bf(float f) {
    union { float f; unsigned u; } c; c.f = f;
    unsigned u = c.u;
    u += 0x7FFFu + ((u >> 16) & 1u);   // RNE; inputs finite
    return (unsigned short)(u >> 16);
}
__device__ __forceinline__ float sigf(float v) { return 1.0f / (1.0f + __expf(-v)); }

// -------- wxform: OIHW f32 -> [tap][co][ci] bf16 (16 KB/tap, L2-resident) ----
__global__ void __launch_bounds__(256) wxform(const float* __restrict__ W,
                                              unsigned short* __restrict__ wpad) {
    int o = blockIdx.x * 256 + threadIdx.x;        // 9*128*64 = 73728
    if (o < 9 * 8192) {
        int tap = o >> 13;
        int r   = o & 8191;
        int co  = r >> 6, ci = r & 63;
        wpad[o] = f2bf(W[co * 576 + ci * 9 + tap]);   // W[co][ci][kh][kw]
    }
}

// x-ring: 10 rows x 18 px x 64 ci bf16. Pixel at local col c (0..17) of ring
// slot so lives at byte (so*18+c)*128; granule g (8 ci) at slot g ^ ((c>>1)&7).
struct SmemT { unsigned short x[10 * 18 * 64]; };   // 23040 B -> 3 blocks/CU

// ============ conv_ring: single-pass, reg-weights, 1 barrier/tile ============
// Block 256 thr = 4 waves (wave = 32-co slice). Tile = 4 rows x 16 cols x 128co;
// strip of 8 tiles (32 rows). Weights never touch LDS: per-tap B-frags are
// register-double-buffered from L2-resident wpad -> no per-tap barrier/drain.
// x staged in-kernel (f32 -> bf16) into ring slots DISJOINT from current reads:
// chunk A issued at tap 0, cvt+written at tap 3; chunk B issued tap 3, done
// tap 6. launch_bounds(256,3): unified VGPR cap ~170 -> NO SPILL (v6/v7 bug).
__global__ void __launch_bounds__(256, 3)
conv_ring(const float* __restrict__ x,
          const unsigned short* __restrict__ wpad,
          const float* __restrict__ bias,
          float* __restrict__ out)
{
    __shared__ __align__(16) SmemT sm;
    __shared__ float red[4];

    const int tid  = threadIdx.x;
    const int coq  = tid >> 6;        // wave id = co quad (32 co)
    const int lane = tid & 63;
    const int lq   = lane >> 4;
    const int lm   = lane & 15;

    const int ct  = blockIdx.x;       // 0..7  col tile (16 wide)
    const int rtg = blockIdx.y;       // 0..3  row strip (32 tall)
    const int n   = blockIdx.z;       // 0..63 image

    const int h0s = rtg * 32;
    const int w0  = ct * 16;
    const float* xn = x + (size_t)n * 1048576;

    // ---- prologue: stage rows h0s..h0s+5 (432 tasks = 8g * 6r * 9wq) ----
    #pragma unroll
    for (int it = 0; it < 2; ++it) {
        int t = it * 256 + tid;
        if (t < 432) {
            int g = t / 54, rem = t % 54;
            int r = rem / 9, wq = rem % 9;
            int h = h0s + r, w = w0 + 2 * wq;     // h <= 101, always valid
            bool ok = (w < 128);
            const float* src = xn + (size_t)(g * 8) * 16384 + h * 128 + w;
            us8 ua, ub;
            #pragma unroll
            for (int j = 0; j < 8; ++j) {
                float2 v = ok ? *(const float2*)(src + j * 16384) : make_float2(0.f, 0.f);
                ua[j] = f2bf(v.x); ub[j] = f2bf(v.y);
            }
            int so = h % 10;
            char* base = (char*)sm.x + (so * 18 + 2 * wq) * 128 + ((g ^ (wq & 7)) << 4);
            *(us8*)(base)       = ua;
            *(us8*)(base + 128) = ub;
        }
    }

    // ---- per-lane weight reg base: co = coq*32 + ntl*16 + lm ----
    const char* wb = (const char*)wpad + ((coq * 32 + lm) << 7) + (lq << 4);
    us8 bbuf[2][4];                    // [parity][ntl*2+kc], all indices static
    #pragma unroll
    for (int f = 0; f < 4; ++f)
        bbuf[0][f] = *(const us8*)(wb + (f >> 1) * 2048 + (f & 1) * 64);   // tap 0

    float bv[2] = { bias[coq * 32 + lm], bias[coq * 32 + 16 + lm] };

    // A-frag byte offsets within a ring row (local col c = lm+kw)
    int sloff[3][2];
    #pragma unroll
    for (int kw = 0; kw < 3; ++kw)
        #pragma unroll
        for (int kc = 0; kc < 2; ++kc)
            sloff[kw][kc] = (lm + kw) * 128 +
                ((((kc << 2) | lq) ^ (((lm + kw) >> 1) & 7)) << 4);

    f32x4 acc[4][2];
    #pragma unroll
    for (int rr = 0; rr < 4; ++rr) {
        acc[rr][0] = (f32x4){0.f, 0.f, 0.f, 0.f};
        acc[rr][1] = (f32x4){0.f, 0.f, 0.f, 0.f};
    }
    float part = 0.0f;

    // staging task coords: task t in [0,288): g=t/36, r=(t%36)/9, wq=t%9
    // chunk A = tasks 0..255 (t=tid), chunk B = tasks 256..287 (threads 0..31)
    const int sAg = tid / 36, sArem = tid % 36;
    const int sAr = sArem / 9, sAwq = sArem % 9;
    const int tB  = 256 + tid;
    const int sBg = tB / 36, sBrem = tB % 36;
    const int sBr = sBrem / 9, sBwq = sBrem % 9;

    __syncthreads();   // prologue x visible

    int sb = h0s % 10;                 // ring slot of tile row 0
    for (int s = 0; s < 8; ++s) {
        float2 fA[8], fB[8];
        bool okA = false, okB = false;

        // ---- 9 taps, no barriers; B reg-double-buffered from L2 ----
        #pragma unroll
        for (int tap = 0; tap < 9; ++tap) {
            const int kh = tap / 3, kw = tap % 3;
            const int tn = (tap == 8) ? 0 : tap + 1;
            #pragma unroll
            for (int f = 0; f < 4; ++f)      // prefetch next tap's B frags
                bbuf[(tap + 1) & 1][f] =
                    *(const us8*)(wb + tn * 16384 + (f >> 1) * 2048 + (f & 1) * 64);

            if (tap == 0 && s < 7) {         // issue chunk-A loads (all threads)
                int h = h0s + s * 4 + 6 + sAr, w = w0 + 2 * sAwq;
                okA = (h < 128) && (w < 128);
                const float* src = xn + (size_t)(sAg * 8) * 16384 + h * 128 + w;
                #pragma unroll
                for (int j = 0; j < 8; ++j)
                    fA[j] = okA ? *(const float2*)(src + j * 16384) : make_float2(0.f, 0.f);
            }

            if (tap == 3 && s < 7) {
                {   // finish chunk A: cvt + ds_write (slots sb+6.., disjoint)
                    us8 ua, ub;
                    #pragma unroll
                    for (int j = 0; j < 8; ++j) { ua[j] = f2bf(fA[j].x); ub[j] = f2bf(fA[j].y); }
                    int so = sb + 6 + sAr; if (so >= 10) so -= 10;
                    char* base = (char*)sm.x + (so * 18 + 2 * sAwq) * 128 +
                                 ((sAg ^ (sAwq & 7)) << 4);
                    *(us8*)(base)       = ua;
                    *(us8*)(base + 128) = ub;
                }
                if (tid < 32) {              // issue chunk-B loads (32 threads)
                    int h = h0s + s * 4 + 6 + sBr, w = w0 + 2 * sBwq;
                    okB = (h < 128) && (w < 128);
                    const float* src = xn + (size_t)(sBg * 8) * 16384 + h * 128 + w;
                    #pragma unroll
                    for (int j = 0; j < 8; ++j)
                        fB[j] = okB ? *(const float2*)(src + j * 16384) : make_float2(0.f, 0.f);
                }
            }

            if (tap == 6 && s < 7 && tid < 32) {   // finish chunk B
                us8 ua, ub;
                #pragma unroll
                for (int j = 0; j < 8; ++j) { ua[j] = f2bf(fB[j].x); ub[j] = f2bf(fB[j].y); }
                int so = sb + 6 + sBr; if (so >= 10) so -= 10;
                char* base = (char*)sm.x + (so * 18 + 2 * sBwq) * 128 +
                             ((sBg ^ (sBwq & 7)) << 4);
                *(us8*)(base)       = ua;
                *(us8*)(base + 128) = ub;
            }

            int q = sb + kh; if (q >= 10) q -= 10;
            #pragma unroll
            for (int kc = 0; kc < 2; ++kc) {
                bf16x8 a[4];
                #pragma unroll
                for (int rr = 0; rr < 4; ++rr) {
                    int so = q + rr; if (so >= 10) so -= 10;
                    a[rr] = *(const bf16x8*)((const char*)sm.x + so * 2304 + sloff[kw][kc]);
                }
                #pragma unroll
                for (int ntl = 0; ntl < 2; ++ntl) {
                    union { us8 u; bf16x8 b; } bu; bu.u = bbuf[tap & 1][ntl * 2 + kc];
                    #pragma unroll
                    for (int rr = 0; rr < 4; ++rr)
                        acc[rr][ntl] = __builtin_amdgcn_mfma_f32_16x16x32_bf16(
                            a[rr], bu.b, acc[rr][ntl], 0, 0, 0);
                }
            }
        }
        #pragma unroll
        for (int f = 0; f < 4; ++f) bbuf[0][f] = bbuf[1][f];   // restore parity

        // ---- per-tile epilogue: pool + bias + sigmoid ----
        #pragma unroll
        for (int p = 0; p < 2; ++p) {
            int ph = rtg * 16 + s * 2 + p;              // pool row
            if (ph < 63) {
                int pwb = ct * 8 + lq * 2;
                #pragma unroll
                for (int ntl = 0; ntl < 2; ++ntl) {
                    f32x4 sv = acc[2 * p][ntl] + acc[2 * p + 1][ntl];  // vert pool
                    float p0 = sv[0] + sv[1];                          // cols (0,1)
                    float p1 = sv[2] + sv[3];                          // cols (2,3)
                    float bbv = bv[ntl];
                    if (pwb < 63)     part += sigf(0.25f * p0 + bbv);
                    if (pwb + 1 < 63) part += sigf(0.25f * p1 + bbv);
                }
            }
        }
        #pragma unroll
        for (int rr = 0; rr < 4; ++rr) {
            acc[rr][0] = (f32x4){0.f, 0.f, 0.f, 0.f};
            acc[rr][1] = (f32x4){0.f, 0.f, 0.f, 0.f};
        }

        sb += 4; if (sb >= 10) sb -= 10;
        __syncthreads();   // staged rows visible; read-done slots reusable
    }

    // ---- block reduce -> one atomicAdd per block ----
    #pragma unroll
    for (int off = 32; off > 0; off >>= 1)
        part += __shfl_down(part, off, 64);
    if (lane == 0) red[coq] = part;
    __syncthreads();
    if (tid == 0) atomicAdd(&out[n], red[0] + red[1] + red[2] + red[3]);
}

extern "C" void kernel_launch(void* const* d_in, const int* in_sizes, int n_in,
                              void* d_out, int out_size, void* d_ws, size_t ws_size,
                              hipStream_t stream) {
    const float* x = (const float*)d_in[0];
    const float* W = (const float*)d_in[1];
    const float* b = (const float*)d_in[2];
    float* out = (float*)d_out;
    unsigned short* wpad = (unsigned short*)d_ws;   // 147,456 B used

    hipMemsetAsync(d_out, 0, 64 * sizeof(float), stream);
    wxform<<<288, 256, 0, stream>>>(W, wpad);
    conv_ring<<<dim3(8, 4, 64), 256, 0, stream>>>(x, wpad, b, out);
}